// Round 16
// baseline (24.773 us; speedup 1.0000x reference)
//
#include <hip/hip_runtime.h>
#include <math.h>

// HungarianMatcher cost matrix:
//   C[i,j] = 5*L1(pred_box_i, tgt_box_j) + 2*focal(tgt class j) - 2*GIoU
// Shapes: pred_logits [BN,NC], pred_boxes [BN,4], tgt_ids [NT], tgt_bbox [NT,4]
// BN=16*900=14400, NC=91, NT=960. Output [BN,NT] fp32.
//
// R15: wave-per-row + 64-VGPR occupancy design. Every kernel so far sat at
// ~68-100 VGPR = 4 waves/SIMD (R1: VGPR_Count=68, just over the 64 cliff).
// __launch_bounds__(256,8) forces <=64 VGPR -> 8 waves/SIMD (2x occupancy).
// Each of the block's 4 waves owns one row: private LDS focal table slice,
// wave-internal lgkmcnt sync, NO __syncthreads. Lane l owns targets
// {l, l+64, ..., l+14*64} (JPT=15), tbox/tid loaded in-loop (L1-hot) to
// keep register pressure ~50. NT dword stores, all accesses lane-coalesced.

#define ALPHA_F   0.25f
#define COST_CLS  2.0f
#define COST_BBOX 5.0f
#define COST_GIOU 2.0f
#define EPS_F     1e-8f

constexpr int THREADS = 256;

__device__ __forceinline__ float focal_entry(float x) {
    const float p  = 1.0f / (1.0f + __expf(-x));
    const float om = 1.0f - p;
    const float neg = (1.0f - ALPHA_F) * p * p * (-__logf(om + EPS_F));
    const float pos = ALPHA_F * om * om        * (-__logf(p  + EPS_F));
    return COST_CLS * (pos - neg) + COST_GIOU;   // GIoU "+2" folded in
}

// ------------------- specialized kernel: wave-per-row ----------------------
template<int NC, int NT>
__global__ __launch_bounds__(THREADS, 8) void matcher_kernel_w(
    const float* __restrict__ logits,   // [BN, NC]
    const float* __restrict__ boxes,    // [BN, 4] cxcywh
    const int*   __restrict__ tids,     // [NT]
    const float* __restrict__ tboxes,   // [NT, 4] cxcywh
    float*       __restrict__ out)      // [BN, NT]
{
    constexpr int NWAVE = THREADS / 64;       // 4 rows per block
    constexpr int JPT   = NT / 64;            // 15 targets per lane
    constexpr int NCP   = 96;                 // padded table stride

    __shared__ float s_cls[NWAVE * NCP];      // 1.5 KB, one slice per wave

    const int tid  = threadIdx.x;
    const int wave = tid >> 6;
    const int lane = tid & 63;
    const int row  = blockIdx.x * NWAVE + wave;

    float* const s_my = s_cls + wave * NCP;

    // ---- private focal table for this wave's row (91 entries, 2 chains) ----
    const float* __restrict__ lg = logits + (size_t)row * NC;
    const int i0 = (lane < NC) ? lane : (NC - 1);
    const int i1 = (lane + 64 < NC) ? (lane + 64) : (NC - 1);
    const float x0 = lg[i0];
    const float x1 = lg[i1];
    // pred box: wave-uniform
    const float4 pb = reinterpret_cast<const float4*>(boxes)[row];

    const float f0 = focal_entry(x0);
    const float f1 = focal_entry(x1);
    if (lane < NC)      s_my[lane]      = f0;
    if (lane + 64 < NC) s_my[lane + 64] = f1;
    // wave-internal visibility: drain this wave's ds_writes; no s_barrier.
    asm volatile("s_waitcnt lgkmcnt(0)" ::: "memory");

    const float px0 = pb.x - 0.5f * pb.z, py0 = pb.y - 0.5f * pb.w;
    const float px1 = pb.x + 0.5f * pb.z, py1 = pb.y + 0.5f * pb.w;
    const float parea = pb.z * pb.w;

    float* __restrict__ obase = out + (size_t)row * NT + lane;
    #pragma unroll 3
    for (int k = 0; k < JPT; ++k) {
        const int j = lane + k * 64;
        const float4 t = reinterpret_cast<const float4*>(tboxes)[j];  // L1-hot
        const int   c  = tids[j];                                     // L1-hot
        const float hw = 0.5f * t.z, hh = 0.5f * t.w;
        const float tx0 = t.x - hw, tx1 = t.x + hw;
        const float ty0 = t.y - hh, ty1 = t.y + hh;
        const float tarea = t.z * t.w;
        // L1 in cxcywh space (abs folds into VOP3 src modifiers)
        const float l1 = (fabsf(pb.x - t.x) + fabsf(pb.y - t.y))
                       + (fabsf(pb.z - t.z) + fabsf(pb.w - t.w));
        // raw intersection extents (feed enclosing box too)
        const float iwr = fminf(px1, tx1) - fmaxf(px0, tx0);
        const float ihr = fminf(py1, ty1) - fmaxf(py0, ty0);
        const float inter = fmaxf(iwr, 0.0f) * fmaxf(ihr, 0.0f);
        const float uni = (parea + tarea) - inter;
        // enclosing box via identity: cw = pw + tw - iwr
        const float cw = (pb.z + t.z) - iwr;
        const float ch = (pb.w + t.w) - ihr;
        const float carea = cw * ch;
        // C = 5*l1 + tbl[c] - 2*(inter*carea + uni^2)/(uni*carea)
        const float num  = fmaf(inter, carea, uni * uni);
        const float rcpd = __builtin_amdgcn_rcpf(uni * carea);
        const float base = fmaf(COST_BBOX, l1, s_my[c]);
        const float v = fmaf(-2.0f * num, rcpd, base);
        __builtin_nontemporal_store(v, obase + k * 64);
    }
}

// ----------------------------- generic fallback -----------------------------
constexpr int GROWS = 8;
__global__ __launch_bounds__(THREADS) void matcher_kernel_g(
    const float* __restrict__ logits, const float* __restrict__ boxes,
    const int* __restrict__ tids, const float* __restrict__ tboxes,
    float* __restrict__ out, int BN, int NC, int NT)
{
    extern __shared__ float s_cls_g[];
    const int tid  = threadIdx.x;
    const int row0 = blockIdx.x * GROWS;
    const int nrows = (BN - row0 < GROWS) ? (BN - row0) : GROWS;

    for (int t = tid; t < nrows * NC; t += THREADS) {
        const int r = t / NC, c = t - r * NC;
        const float x = logits[(size_t)(row0 + r) * NC + c];
        const float p  = 1.0f / (1.0f + expf(-x));
        const float om = 1.0f - p;
        const float neg = (1.0f - ALPHA_F) * p * p * (-logf(om + EPS_F));
        const float pos = ALPHA_F * om * om        * (-logf(p + EPS_F));
        s_cls_g[r * NC + c] = pos - neg;
    }
    __syncthreads();

    for (int r = 0; r < nrows; ++r) {
        const int row = row0 + r;
        const float4 pb = reinterpret_cast<const float4*>(boxes)[row];
        const float px0 = pb.x - 0.5f * pb.z, py0 = pb.y - 0.5f * pb.w;
        const float px1 = pb.x + 0.5f * pb.z, py1 = pb.y + 0.5f * pb.w;
        const float parea = pb.z * pb.w;
        for (int j = tid; j < NT; j += THREADS) {
            const float4 b = reinterpret_cast<const float4*>(tboxes)[j];
            const float bx0 = b.x - 0.5f * b.z, by0 = b.y - 0.5f * b.w;
            const float bx1 = b.x + 0.5f * b.z, by1 = b.y + 0.5f * b.w;
            const float l1 = fabsf(pb.x - b.x) + fabsf(pb.y - b.y)
                           + fabsf(pb.z - b.z) + fabsf(pb.w - b.w);
            const float iw = fmaxf(fminf(px1, bx1) - fmaxf(px0, bx0), 0.0f);
            const float ih = fmaxf(fminf(py1, by1) - fmaxf(py0, by0), 0.0f);
            const float inter = iw * ih;
            const float uni = parea + b.z * b.w - inter;
            const float iou = inter / uni;
            const float cw = fmaxf(px1, bx1) - fminf(px0, bx0);
            const float ch = fmaxf(py1, by1) - fminf(py0, by0);
            const float carea = cw * ch;
            const float giou = iou - (carea - uni) / carea;
            const float ccls = s_cls_g[r * NC + tids[j]];
            out[(size_t)row * NT + j] = COST_BBOX * l1 + COST_CLS * ccls - COST_GIOU * giou;
        }
        __syncthreads();
    }
}

extern "C" void kernel_launch(void* const* d_in, const int* in_sizes, int n_in,
                              void* d_out, int out_size, void* d_ws, size_t ws_size,
                              hipStream_t stream) {
    const float* logits = (const float*)d_in[0];
    const float* boxes  = (const float*)d_in[1];
    const int*   tids   = (const int*)d_in[2];
    const float* tboxes = (const float*)d_in[3];
    float* out = (float*)d_out;

    const int BN = in_sizes[1] / 4;       // 14400
    const int NC = in_sizes[0] / BN;      // 91
    const int NT = in_sizes[2];           // 960

    if (NC == 91 && NT == 960 && BN % 4 == 0) {
        matcher_kernel_w<91, 960><<<BN / 4, THREADS, 0, stream>>>(
            logits, boxes, tids, tboxes, out);
    } else {
        const int grid = (BN + GROWS - 1) / GROWS;
        const size_t shmem = (size_t)GROWS * NC * sizeof(float);
        matcher_kernel_g<<<grid, THREADS, shmem, stream>>>(
            logits, boxes, tids, tboxes, out, BN, NC, NT);
    }
}